// Round 1
// baseline (191.224 us; speedup 1.0000x reference)
//
#include <hip/hip_runtime.h>
#include <hip/hip_bf16.h>

#define EMB 10
#define DIN 36    // 2*EMB + 16 numeric
#define HID 128
#define BM  128   // rows per block

typedef __attribute__((ext_vector_type(8))) short short8;   // bf16x8 MFMA frag
typedef __attribute__((ext_vector_type(4))) float f32x4;    // fp32x4 acc frag

__device__ __forceinline__ short bf16_hi(float v) {
  __hip_bfloat16 h = __float2bfloat16(v);
  return *reinterpret_cast<short*>(&h);
}
__device__ __forceinline__ float bf16_to_f(short s) {
  __hip_bfloat16 h = *reinterpret_cast<__hip_bfloat16*>(&s);
  return __bfloat162float(h);
}

// Pack W1 (36x128) + b1 (as k=36 row, bias trick) into hi/lo bf16 B-fragments,
// K padded to 64. Layout: [term(2)][ct(8)][ks(2)][lane(64)][e(8)] bf16.
// B frag mapping (mfma_f32_16x16x32_bf16): col = ct*16+(lane&15),
// k = ks*32 + (lane>>4)*8 + e.
__global__ void prep_kernel(const float* __restrict__ W1, const float* __restrict__ b1,
                            short* __restrict__ Bpack) {
  int b = blockIdx.x;          // 32 blocks
  int term = b >> 4;           // 0 = hi, 1 = lo
  int ct   = (b >> 1) & 7;
  int ks   = b & 1;
  int l = threadIdx.x;         // 0..63
  int col = ct * 16 + (l & 15);
  int kb  = ks * 32 + (l >> 4) * 8;
  short8 o;
#pragma unroll
  for (int e = 0; e < 8; ++e) {
    int k = kb + e;
    float v = 0.0f;
    if (k < DIN)       v = W1[k * HID + col];
    else if (k == DIN) v = b1[col];
    short hb = bf16_hi(v);
    o[e] = (term == 0) ? hb : bf16_hi(v - bf16_to_f(hb));
  }
  *(short8*)(Bpack + (size_t)(((term * 8 + ct) * 2 + ks) * 64 + l) * 8) = o;
}

__global__ __launch_bounds__(256, 3)
void fused_kernel(const int* __restrict__ t1, const int* __restrict__ t2,
                  const float* __restrict__ numf,
                  const float* __restrict__ tab1, const float* __restrict__ tab2,
                  const short* __restrict__ Bpack,
                  const float* __restrict__ W2, const float* __restrict__ b2,
                  float* __restrict__ out, int N) {
  __shared__ float E1[BM + 2][11];   // halo rows, padded stride 11 (bank spread)
  __shared__ float E2[BM + 6][11];
  __shared__ short Afrag[2][BM / 16][2][64][8];  // [term][rt][ks][lane][e] 32 KB
  __shared__ float W2s[HID];

  const int tid = threadIdx.x;
  const long base = (long)blockIdx.x * BM;
  const long row = base + tid;                       // valid when tid < BM
  const bool rv = (tid < BM) && (row < (long)N);

  // prefetch this row's numeric features
  float4 nf0, nf1, nf2, nf3;
  if (rv) {
    const float4* np = (const float4*)(numf + row * 16);
    nf0 = np[0]; nf1 = np[1]; nf2 = np[2]; nf3 = np[3];
  }
  // E1 halo gather: threads 0..129
  if (tid < BM + 2) {
    long g = base - 1 + tid;
    if (g >= 0 && g < N) {
      const float* src = tab1 + (long)t1[g] * EMB;
#pragma unroll
      for (int i = 0; i < EMB; ++i) E1[tid][i] = src[i];
    }
  }
  // E2 halo gather: threads 122..255
  {
    int h = tid - (256 - (BM + 6));
    if (h >= 0) {
      long g = base - 3 + h;
      if (g >= 0 && g < N) {
        const float* src = tab2 + (long)t2[g] * EMB;
#pragma unroll
        for (int i = 0; i < EMB; ++i) E2[h][i] = src[i];
      }
    }
  }
  if (tid >= 128) W2s[tid - 128] = W2[tid - 128];
  __syncthreads();

  // Build combined[36] + bias slot, split hi/lo, write A-fragments
  if (rv) {
    float c[DIN + 1];
    {
      float s[EMB] = {0,0,0,0,0,0,0,0,0,0};
      int cnt = 0;
#pragma unroll
      for (int d = 0; d < 3; ++d) {
        long g = row - 1 + d;
        if (g >= 0 && g < N) {
          int h = tid + d;
#pragma unroll
          for (int i = 0; i < EMB; ++i) s[i] += E1[h][i];
          ++cnt;
        }
      }
      float inv = 1.0f / (float)cnt;
#pragma unroll
      for (int i = 0; i < EMB; ++i) c[i] = s[i] * inv;
    }
    {
      float s[EMB] = {0,0,0,0,0,0,0,0,0,0};
      int cnt = 0;
#pragma unroll
      for (int d = 0; d < 7; ++d) {
        long g = row - 3 + d;
        if (g >= 0 && g < N) {
          int h = tid + d;
#pragma unroll
          for (int i = 0; i < EMB; ++i) s[i] += E2[h][i];
          ++cnt;
        }
      }
      float inv = 1.0f / (float)cnt;
#pragma unroll
      for (int i = 0; i < EMB; ++i) c[EMB + i] = s[i] * inv;
    }
    c[20] = nf0.x; c[21] = nf0.y; c[22] = nf0.z; c[23] = nf0.w;
    c[24] = nf1.x; c[25] = nf1.y; c[26] = nf1.z; c[27] = nf1.w;
    c[28] = nf2.x; c[29] = nf2.y; c[30] = nf2.z; c[31] = nf2.w;
    c[32] = nf3.x; c[33] = nf3.y; c[34] = nf3.z; c[35] = nf3.w;
    c[DIN] = 1.0f;   // bias slot multiplies packed b1 row

    const int rt = tid >> 4;       // row-tile 0..7
    const int wr = tid & 15;       // row within tile
#pragma unroll
    for (int g = 0; g < 8; ++g) {  // k-octet 0..7 (k = g*8+e)
      short8 hi8, lo8;
#pragma unroll
      for (int e = 0; e < 8; ++e) {
        int k = g * 8 + e;
        float v = (k <= DIN) ? c[k] : 0.0f;
        short hb = bf16_hi(v);
        hi8[e] = hb;
        lo8[e] = bf16_hi(v - bf16_to_f(hb));
      }
      int ks = g >> 2;
      int lane = (g & 3) * 16 + wr;
      *(short8*)&Afrag[0][rt][ks][lane][0] = hi8;
      *(short8*)&Afrag[1][rt][ks][lane][0] = lo8;
    }
  }
  __syncthreads();

  // MFMA phase: 4 waves x 2 row-tiles each
  const int wid = tid >> 6;
  const int l = tid & 63;

  short8 a[2][2][2];  // [rtl][term][ks]
#pragma unroll
  for (int rtl = 0; rtl < 2; ++rtl) {
    int rt = wid * 2 + rtl;
#pragma unroll
    for (int term = 0; term < 2; ++term)
#pragma unroll
      for (int ks = 0; ks < 2; ++ks)
        a[rtl][term][ks] = *(const short8*)&Afrag[term][rt][ks][l][0];
  }

  float part[2][4] = {{0,0,0,0},{0,0,0,0}};
#pragma unroll
  for (int ct = 0; ct < 8; ++ct) {
    short8 bb[2][2];
#pragma unroll
    for (int term = 0; term < 2; ++term)
#pragma unroll
      for (int ks = 0; ks < 2; ++ks)
        bb[term][ks] = *(const short8*)(Bpack +
            (size_t)(((term * 8 + ct) * 2 + ks) * 64 + l) * 8);
    float w2c = W2s[ct * 16 + (l & 15)];
#pragma unroll
    for (int rtl = 0; rtl < 2; ++rtl) {
      f32x4 acc = {0.0f, 0.0f, 0.0f, 0.0f};
#pragma unroll
      for (int ks = 0; ks < 2; ++ks) {
        acc = __builtin_amdgcn_mfma_f32_16x16x32_bf16(a[rtl][0][ks], bb[0][ks], acc, 0, 0, 0);
        acc = __builtin_amdgcn_mfma_f32_16x16x32_bf16(a[rtl][1][ks], bb[0][ks], acc, 0, 0, 0);
        acc = __builtin_amdgcn_mfma_f32_16x16x32_bf16(a[rtl][0][ks], bb[1][ks], acc, 0, 0, 0);
      }
#pragma unroll
      for (int r = 0; r < 4; ++r) {
        float hv = fmaxf(acc[r], 0.0f);    // relu(h + b1) — b1 folded via bias slot
        part[rtl][r] += hv * w2c;          // partial W2 dot
      }
    }
  }
  // reduce the W2 dot across the 16 column-lanes
#pragma unroll
  for (int off = 1; off < 16; off <<= 1) {
#pragma unroll
    for (int rtl = 0; rtl < 2; ++rtl)
#pragma unroll
      for (int r = 0; r < 4; ++r)
        part[rtl][r] += __shfl_xor(part[rtl][r], off, 64);
  }
  if ((l & 15) < 4) {
    float b2v = b2[0];
#pragma unroll
    for (int rtl = 0; rtl < 2; ++rtl) {
      int rt = wid * 2 + rtl;
      long grow = base + rt * 16 + (l >> 4) * 4 + (l & 15);
      if (grow < N) {
        float x = part[rtl][l & 15] + b2v;
        out[grow] = 1.0f / (1.0f + expf(-x));
      }
    }
  }
}

extern "C" void kernel_launch(void* const* d_in, const int* in_sizes, int n_in,
                              void* d_out, int out_size, void* d_ws, size_t ws_size,
                              hipStream_t stream) {
  const int*   t1   = (const int*)d_in[0];
  const int*   t2   = (const int*)d_in[1];
  const float* numf = (const float*)d_in[2];
  const float* tab1 = (const float*)d_in[3];
  const float* tab2 = (const float*)d_in[4];
  const float* W1   = (const float*)d_in[5];
  const float* b1   = (const float*)d_in[6];
  const float* W2   = (const float*)d_in[7];
  const float* b2   = (const float*)d_in[8];
  float* out = (float*)d_out;
  const int N = in_sizes[0];
  short* Bpack = (short*)d_ws;   // 32 KB

  hipLaunchKernelGGL(prep_kernel, dim3(32), dim3(64), 0, stream, W1, b1, Bpack);
  int nblk = (N + BM - 1) / BM;
  hipLaunchKernelGGL(fused_kernel, dim3(nblk), dim3(256), 0, stream,
                     t1, t2, numf, tab1, tab2, Bpack, W2, b2, out, N);
}